// Round 7
// baseline (479.140 us; speedup 1.0000x reference)
//
#include <hip/hip_runtime.h>
#include <hip/hip_bf16.h>

typedef unsigned short u16;
typedef __attribute__((ext_vector_type(8))) short short8;
typedef __attribute__((ext_vector_type(4))) float floatx4;

#define NB 4
#define NT 2048
#define ND 1024
#define NH 2048
#define NO 1024
#define NE 8
#define NTOK (NB * NT)   // 8192 tokens

#define BM 128
#define BN 128
#define BK 32            // u16 units; 64 B per LDS row

__device__ __forceinline__ u16 f2bf(float f) {
  __hip_bfloat16 h = __float2bfloat16(f);
  return *reinterpret_cast<u16*>(&h);
}

__device__ __forceinline__ float bf2f(unsigned u) {
  return __uint_as_float(u << 16);
}

// async 16B global->LDS (DMA: lane i lands at ldsbase + i*16)
__device__ __forceinline__ void async16(const u16* g, u16* l) {
  __builtin_amdgcn_global_load_lds(
      (const __attribute__((address_space(1))) void*)g,
      (__attribute__((address_space(3))) void*)l, 16, 0, 0);
}

// Shared-memory union: transpose tile / gemm tiles / router tables
union Smem {
  float tile[64][65];                                  // 16640 B
  struct { u16 As[BM * BK]; u16 Bs[BN * BK];
           int ent_s[BM]; float w_s[BM]; } g;          // 17408 B
  struct { int se0[32]; int se1[32];
           float sw0[32]; float sw1[32]; } r;          // 512 B
};

// ---------------------------------------------------------------------------
// Transpose + fp32->bf16 (device fn): RxC row-major -> CxR bf16, 64x64 tile
// ---------------------------------------------------------------------------
__device__ void transpose_tile(const float* __restrict__ in, u16* __restrict__ out,
                               int R, int C, int r0, int c0,
                               float (*tile)[65], int t) {
#pragma unroll
  for (int i = 0; i < 4; ++i) {
    int idx = t + i * 256;                  // 64 r x 16 cq
    int rr = idx >> 4, cq = idx & 15;
    float4 v = *(const float4*)&in[(size_t)(r0 + rr) * C + c0 + cq * 4];
    tile[rr][cq * 4 + 0] = v.x; tile[rr][cq * 4 + 1] = v.y;
    tile[rr][cq * 4 + 2] = v.z; tile[rr][cq * 4 + 3] = v.w;
  }
  __syncthreads();
#pragma unroll
  for (int i = 0; i < 4; ++i) {
    int idx = t + i * 256;                  // 64 c x 16 rq
    int c = idx >> 4, rq = idx & 15;
    uint2 p;
    p.x = (unsigned)f2bf(tile[rq * 4 + 0][c]) | ((unsigned)f2bf(tile[rq * 4 + 1][c]) << 16);
    p.y = (unsigned)f2bf(tile[rq * 4 + 2][c]) | ((unsigned)f2bf(tile[rq * 4 + 3][c]) << 16);
    *(uint2*)&out[(size_t)(c0 + c) * R + r0 + rq * 4] = p;
  }
}

// ---------------------------------------------------------------------------
// prep1: blocks [0,4096) transpose W1 -> w1t; blocks [4096,4352) = router.
// Router: 32 tokens/block, 8 lanes/token, one atomicAdd/expert/block.
// ---------------------------------------------------------------------------
__global__ __launch_bounds__(256) void prep1_kernel(
    const float* __restrict__ W1, u16* __restrict__ w1t,
    const float* __restrict__ x, const float* __restrict__ Wg,
    const float* __restrict__ bg, u16* __restrict__ xbf,
    int* __restrict__ counts, int* __restrict__ entries,
    float* __restrict__ wts) {
  __shared__ Smem sm;
  int t = threadIdx.x;
  int b = blockIdx.x;
  if (b < 4096) {                 // W1: (E, ND, NH) -> (E, NH, ND)
    int e = b >> 9, r = b & 511;
    transpose_tile(W1 + (size_t)e * ND * NH, w1t + (size_t)e * ND * NH,
                   ND, NH, (r >> 5) * 64, (r & 31) * 64, sm.tile, t);
    return;
  }
  int br = b - 4096;
  int tl = t >> 3;                 // token slot 0..31
  int l8 = t & 7;
  int tok = br * 32 + tl;

  const float* xrow = x + (size_t)tok * ND;
  u16* xbrow = xbf + (size_t)tok * ND;
  float acc[8] = {};
#pragma unroll 4
  for (int i = 0; i < 32; ++i) {
    int d0 = l8 * 4 + i * 32;
    float4 xv = *(const float4*)&xrow[d0];
    uint2 p;
    p.x = (unsigned)f2bf(xv.x) | ((unsigned)f2bf(xv.y) << 16);
    p.y = (unsigned)f2bf(xv.z) | ((unsigned)f2bf(xv.w) << 16);
    *(uint2*)&xbrow[d0] = p;
    const float* wr = Wg + (size_t)d0 * NE;
#pragma unroll
    for (int j = 0; j < 4; ++j) {
      float xs = (j == 0) ? xv.x : (j == 1) ? xv.y : (j == 2) ? xv.z : xv.w;
      float4 w0 = *(const float4*)&wr[j * NE];
      float4 w1 = *(const float4*)&wr[j * NE + 4];
      acc[0] += xs * w0.x; acc[1] += xs * w0.y;
      acc[2] += xs * w0.z; acc[3] += xs * w0.w;
      acc[4] += xs * w1.x; acc[5] += xs * w1.y;
      acc[6] += xs * w1.z; acc[7] += xs * w1.w;
    }
  }
#pragma unroll
  for (int off = 4; off; off >>= 1)
#pragma unroll
    for (int k = 0; k < 8; ++k) acc[k] += __shfl_down(acc[k], off, 8);

  if (l8 == 0) {
    float best = -1e30f, second = -1e30f;
    int e0 = 0, e1 = 0;
#pragma unroll
    for (int i = 0; i < NE; ++i) {
      float L = acc[i] + bg[i];
      if (L > best) { second = best; e1 = e0; best = L; e0 = i; }
      else if (L > second) { second = L; e1 = i; }
    }
    float p1 = __expf(second - best);
    float inv = 1.f / (1.f + p1);
    sm.r.se0[tl] = e0; sm.r.se1[tl] = e1;
    sm.r.sw0[tl] = inv; sm.r.sw1[tl] = p1 * inv;
  }
  __syncthreads();

  if (t < NE) {
    int e = t;
    int c = 0;
#pragma unroll
    for (int k = 0; k < 32; ++k) c += (sm.r.se0[k] == e) + (sm.r.se1[k] == e);
    int pos = atomicAdd(&counts[e * 32], c);   // padded: 128 B per expert
    int base = br * 32;
    for (int k = 0; k < 32; ++k) {
      if (sm.r.se0[k] == e) { entries[e * NTOK + pos] = (base + k) * 2;     wts[e * NTOK + pos] = sm.r.sw0[k]; ++pos; }
      if (sm.r.se1[k] == e) { entries[e * NTOK + pos] = (base + k) * 2 + 1; wts[e * NTOK + pos] = sm.r.sw1[k]; ++pos; }
    }
  }
}

// ---------------------------------------------------------------------------
// gemm1 fused with W2 transpose: blocks [0,4096) transpose W2 (overlapped),
// blocks [4096,12288) = gemm1: relu(X*W1+b1) -> hbuf.
// BK=32, conflict-free swizzle, base-pointer + const-offset fragment reads.
// XCD-pinned: expert = b&7, n innermost.
// ---------------------------------------------------------------------------
__global__ __launch_bounds__(256) void gemm1_kernel(
    const float* __restrict__ W2, u16* __restrict__ w2t,
    const u16* __restrict__ xbf, const u16* __restrict__ w1t,
    const float* __restrict__ b1, const int* __restrict__ counts,
    const int* __restrict__ entries, u16* __restrict__ hbuf) {
  __shared__ Smem sm;
  int t = threadIdx.x;
  if (blockIdx.x < 4096) {        // W2: (E, NH, NO) -> (E, NO, NH)
    int bb = blockIdx.x;
    int e = bb >> 9, r = bb & 511;
    transpose_tile(W2 + (size_t)e * NH * NO, w2t + (size_t)e * NH * NO,
                   NH, NO, (r >> 4) * 64, (r & 15) * 64, sm.tile, t);
    return;
  }
  int b = blockIdx.x - 4096;
  int e = b & 7;
  int r = b >> 3;
  int m0 = (r >> 4) * BM;          // NH/BN = 16 n-tiles innermost
  int n0 = (r & 15) * BN;
  int cnt = counts[e * 32];
  if (m0 >= cnt) return;
  int rem = cnt - m0; if (rem > BM) rem = BM;

  u16* As = sm.g.As; u16* Bs = sm.g.Bs; int* ent_s = sm.g.ent_s;
  if (t < BM) ent_s[t] = (t < rem) ? entries[e * NTOK + m0 + t] : entries[e * NTOK];
  __syncthreads();

  int lane = t & 63, wv = t >> 6;
  int rl0 = wv * 32 + (lane >> 2);         // staging rows
  int rl1 = rl0 + 16;
  int pg = (((lane & 3) ^ ((rl0 >> 1) & 3))) * 8;   // swizzled GLOBAL chunk
  const u16* gA0 = xbf + (size_t)(ent_s[rl0] >> 1) * ND + pg;
  const u16* gA1 = xbf + (size_t)(ent_s[rl1] >> 1) * ND + pg;
  const u16* Bbase = w1t + (size_t)e * NH * ND + (size_t)n0 * ND;
  const u16* gB0 = Bbase + (size_t)rl0 * ND + pg;
  const u16* gB1 = Bbase + (size_t)rl1 * ND + pg;
  u16* lA0 = As + (wv * 32) * BK;          // wave-uniform LDS bases
  u16* lA1 = As + (wv * 32 + 16) * BK;
  u16* lB0 = Bs + (wv * 32) * BK;
  u16* lB1 = Bs + (wv * 32 + 16) * BK;

  int waveM = (wv >> 1) * 64, waveN = (wv & 1) * 64;
  int rA = lane & 15, quad = lane >> 4;
  int cR = (quad ^ ((rA >> 1) & 3)) * 8;   // read-side phys chunk
  const u16* aBase = &As[(waveM + rA) * BK + cR];
  const u16* bBase = &Bs[(waveN + rA) * BK + cR];

  floatx4 acc[4][4] = {};
  for (int k0 = 0; k0 < ND; k0 += BK) {
    async16(gA0 + k0, lA0);
    async16(gA1 + k0, lA1);
    async16(gB0 + k0, lB0);
    async16(gB1 + k0, lB1);
    __syncthreads();
    short8 a[4], bb[4];
#pragma unroll
    for (int i = 0; i < 4; ++i) {
      a[i]  = *(const short8*)(aBase + i * (16 * BK));
      bb[i] = *(const short8*)(bBase + i * (16 * BK));
    }
#pragma unroll
    for (int i = 0; i < 4; ++i)
#pragma unroll
      for (int j = 0; j < 4; ++j)
        acc[i][j] = __builtin_amdgcn_mfma_f32_16x16x32_bf16(a[i], bb[j], acc[i][j], 0, 0, 0);
    __syncthreads();
  }

#pragma unroll
  for (int i = 0; i < 4; ++i)
#pragma unroll
    for (int rr = 0; rr < 4; ++rr) {
      int lm = waveM + i * 16 + quad * 4 + rr;
      if (lm >= rem) continue;
      int ent = ent_s[lm];
      u16* dst = hbuf + (size_t)ent * NH + n0;
#pragma unroll
      for (int j = 0; j < 4; ++j) {
        int col = waveN + j * 16 + rA;
        float v = acc[i][j][rr] + b1[e * NH + n0 + col];
        dst[col] = f2bf(fmaxf(v, 0.f));
      }
    }
}

// ---------------------------------------------------------------------------
// GEMM2: eo[entry] = (H*W2 + b2) * gate_w. Same structure, K=NH.
// ---------------------------------------------------------------------------
__global__ __launch_bounds__(256) void gemm2_kernel(
    const u16* __restrict__ hbuf, const u16* __restrict__ w2t,
    const float* __restrict__ b2, const int* __restrict__ counts,
    const int* __restrict__ entries, const float* __restrict__ wts,
    u16* __restrict__ eo) {
  __shared__ Smem sm;
  int b = blockIdx.x;
  int e = b & 7;
  int r = b >> 3;
  int m0 = (r >> 3) * BM;          // NO/BN = 8 n-tiles innermost
  int n0 = (r & 7) * BN;
  int cnt = counts[e * 32];
  if (m0 >= cnt) return;
  int rem = cnt - m0; if (rem > BM) rem = BM;

  u16* As = sm.g.As; u16* Bs = sm.g.Bs;
  int* ent_s = sm.g.ent_s; float* w_s = sm.g.w_s;
  int t = threadIdx.x;
  if (t < BM) {
    int src = (t < rem) ? (e * NTOK + m0 + t) : (e * NTOK);
    ent_s[t] = entries[src];
    w_s[t] = wts[src];
  }
  __syncthreads();

  int lane = t & 63, wv = t >> 6;
  int rl0 = wv * 32 + (lane >> 2);
  int rl1 = rl0 + 16;
  int pg = (((lane & 3) ^ ((rl0 >> 1) & 3))) * 8;
  const u16* gA0 = hbuf + (size_t)ent_s[rl0] * NH + pg;
  const u16* gA1 = hbuf + (size_t)ent_s[rl1] * NH + pg;
  const u16* Bbase = w2t + (size_t)e * NO * NH + (size_t)n0 * NH;
  const u16* gB0 = Bbase + (size_t)rl0 * NH + pg;
  const u16* gB1 = Bbase + (size_t)rl1 * NH + pg;
  u16* lA0 = As + (wv * 32) * BK;
  u16* lA1 = As + (wv * 32 + 16) * BK;
  u16* lB0 = Bs + (wv * 32) * BK;
  u16* lB1 = Bs + (wv * 32 + 16) * BK;

  int waveM = (wv >> 1) * 64, waveN = (wv & 1) * 64;
  int rA = lane & 15, quad = lane >> 4;
  int cR = (quad ^ ((rA >> 1) & 3)) * 8;
  const u16* aBase = &As[(waveM + rA) * BK + cR];
  const u16* bBase = &Bs[(waveN + rA) * BK + cR];

  floatx4 acc[4][4] = {};
  for (int k0 = 0; k0 < NH; k0 += BK) {
    async16(gA0 + k0, lA0);
    async16(gA1 + k0, lA1);
    async16(gB0 + k0, lB0);
    async16(gB1 + k0, lB1);
    __syncthreads();
    short8 a[4], bb[4];
#pragma unroll
    for (int i = 0; i < 4; ++i) {
      a[i]  = *(const short8*)(aBase + i * (16 * BK));
      bb[i] = *(const short8*)(bBase + i * (16 * BK));
    }
#pragma unroll
    for (int i = 0; i < 4; ++i)
#pragma unroll
      for (int j = 0; j < 4; ++j)
        acc[i][j] = __builtin_amdgcn_mfma_f32_16x16x32_bf16(a[i], bb[j], acc[i][j], 0, 0, 0);
    __syncthreads();
  }

#pragma unroll
  for (int i = 0; i < 4; ++i)
#pragma unroll
    for (int rr = 0; rr < 4; ++rr) {
      int lm = waveM + i * 16 + quad * 4 + rr;
      if (lm >= rem) continue;
      int ent = ent_s[lm];
      float w = w_s[lm];
      u16* dst = eo + (size_t)ent * NO + n0;
#pragma unroll
      for (int j = 0; j < 4; ++j) {
        int col = waveN + j * 16 + rA;
        float v = (acc[i][j][rr] + b2[e * NO + n0 + col]) * w;
        dst[col] = f2bf(v);
      }
    }
}

// ---------------------------------------------------------------------------
// Combine: out[tok] = eo[2*tok] + eo[2*tok+1]
// ---------------------------------------------------------------------------
__global__ __launch_bounds__(256) void combine_kernel(
    const u16* __restrict__ eo, float* __restrict__ out) {
  size_t idx = (size_t)blockIdx.x * 256 + threadIdx.x;
  size_t tok = idx >> 8;
  int oq = (int)(idx & 255) * 4;
  const u16* p0 = eo + (tok * 2) * NO + oq;
  const u16* p1 = p0 + NO;
  uint2 ua = *(const uint2*)p0;
  uint2 ub = *(const uint2*)p1;
  float4 o;
  o.x = bf2f(ua.x & 0xffff) + bf2f(ub.x & 0xffff);
  o.y = bf2f(ua.x >> 16)    + bf2f(ub.x >> 16);
  o.z = bf2f(ua.y & 0xffff) + bf2f(ub.y & 0xffff);
  o.w = bf2f(ua.y >> 16)    + bf2f(ub.y >> 16);
  *(float4*)&out[tok * NO + oq] = o;
}

// ---------------------------------------------------------------------------
extern "C" void kernel_launch(void* const* d_in, const int* in_sizes, int n_in,
                              void* d_out, int out_size, void* d_ws, size_t ws_size,
                              hipStream_t stream) {
  (void)in_sizes; (void)n_in; (void)out_size; (void)ws_size;
  const float* x  = (const float*)d_in[0];
  const float* Wg = (const float*)d_in[2];
  const float* bg = (const float*)d_in[3];
  const float* W1 = (const float*)d_in[4];
  const float* b1 = (const float*)d_in[5];
  const float* W2 = (const float*)d_in[6];
  const float* b2 = (const float*)d_in[7];
  float* out = (float*)d_out;

  char* ws = (char*)d_ws;
  size_t off = 0;
  int*   counts  = (int*)(ws + off);   off += NE * 32 * 4;               // padded
  int*   entries = (int*)(ws + off);   off += (size_t)NE * NTOK * 4;
  float* wts     = (float*)(ws + off); off += (size_t)NE * NTOK * 4;
  u16*   xbf     = (u16*)(ws + off);   off += (size_t)NTOK * ND * 2;
  u16*   w1t     = (u16*)(ws + off);   off += (size_t)NE * NH * ND * 2;
  u16*   w2t     = (u16*)(ws + off);   off += (size_t)NE * NO * NH * 2;
  u16*   hbuf    = (u16*)(ws + off);   off += (size_t)NTOK * 2 * NH * 2;
  u16*   eo      = w1t;  // alias: w1t dead after gemm1

  hipMemsetAsync(counts, 0, NE * 32 * 4, stream);

  prep1_kernel<<<4096 + NTOK / 32, 256, 0, stream>>>(
      W1, w1t, x, Wg, bg, xbf, counts, entries, wts);
  gemm1_kernel<<<4096 + NE * (NTOK / BM) * (NH / BN), 256, 0, stream>>>(
      W2, w2t, xbf, w1t, b1, counts, entries, hbuf);
  gemm2_kernel<<<NE * (NTOK / BM) * (NO / BN), 256, 0, stream>>>(
      hbuf, w2t, b2, counts, entries, wts, eo);
  combine_kernel<<<(NTOK * NO / 4) / 256, 256, 0, stream>>>(eo, out);
}

// Round 8
// 441.763 us; speedup vs baseline: 1.0846x; 1.0846x over previous
//
#include <hip/hip_runtime.h>
#include <hip/hip_bf16.h>

typedef unsigned short u16;
typedef __attribute__((ext_vector_type(8))) short short8;
typedef __attribute__((ext_vector_type(4))) float floatx4;

#define NB 4
#define NT 2048
#define ND 1024
#define NH 2048
#define NO 1024
#define NE 8
#define NTOK (NB * NT)   // 8192 tokens

#define BM 128
#define BN 128
#define BK 32            // u16 units; 64 B per LDS row

__device__ __forceinline__ u16 f2bf(float f) {
  __hip_bfloat16 h = __float2bfloat16(f);
  return *reinterpret_cast<u16*>(&h);
}

__device__ __forceinline__ float bf2f(unsigned u) {
  return __uint_as_float(u << 16);
}

// async 16B global->LDS (DMA: lane i lands at ldsbase + i*16)
__device__ __forceinline__ void async16(const u16* g, u16* l) {
  __builtin_amdgcn_global_load_lds(
      (const __attribute__((address_space(1))) void*)g,
      (__attribute__((address_space(3))) void*)l, 16, 0, 0);
}

// ---------------------------------------------------------------------------
// Transpose + fp32->bf16: per-expert RxC row-major -> CxR bf16.
// Write phase: 16-B uint4 stores (8 lanes = 128 B runs); LDS column reads
// are 2-way bank-aliased only (free): bank = (8*rq + j + c) mod 32.
// ---------------------------------------------------------------------------
__global__ __launch_bounds__(256) void transpose_cvt(
    const float* __restrict__ in, u16* __restrict__ out, int R, int C) {
  __shared__ float tile[64][65];
  int e = blockIdx.z;
  in  += (size_t)e * R * C;
  out += (size_t)e * R * C;
  int c0 = blockIdx.x * 64, r0 = blockIdx.y * 64;
  int t = threadIdx.x;
#pragma unroll
  for (int i = 0; i < 4; ++i) {
    int idx = t + i * 256;                  // 64 r x 16 cq
    int r = idx >> 4, cq = idx & 15;
    float4 v = *(const float4*)&in[(size_t)(r0 + r) * C + c0 + cq * 4];
    tile[r][cq * 4 + 0] = v.x; tile[r][cq * 4 + 1] = v.y;
    tile[r][cq * 4 + 2] = v.z; tile[r][cq * 4 + 3] = v.w;
  }
  __syncthreads();
#pragma unroll
  for (int i = 0; i < 2; ++i) {
    int idx = t + i * 256;                  // 64 c x 8 rq-chunks of 8
    int c = idx >> 3, rq = idx & 7;
    uint4 p;
    p.x = (unsigned)f2bf(tile[rq * 8 + 0][c]) | ((unsigned)f2bf(tile[rq * 8 + 1][c]) << 16);
    p.y = (unsigned)f2bf(tile[rq * 8 + 2][c]) | ((unsigned)f2bf(tile[rq * 8 + 3][c]) << 16);
    p.z = (unsigned)f2bf(tile[rq * 8 + 4][c]) | ((unsigned)f2bf(tile[rq * 8 + 5][c]) << 16);
    p.w = (unsigned)f2bf(tile[rq * 8 + 6][c]) | ((unsigned)f2bf(tile[rq * 8 + 7][c]) << 16);
    *(uint4*)&out[(size_t)(c0 + c) * R + r0 + rq * 8] = p;
  }
}

// ---------------------------------------------------------------------------
// Router: 32 tokens/block, 8 lanes/token. Per-block LDS choice table;
// ONE atomicAdd per expert per block, counters padded to 128 B apart.
// ---------------------------------------------------------------------------
__global__ __launch_bounds__(256) void router_kernel(
    const float* __restrict__ x, const float* __restrict__ Wg,
    const float* __restrict__ bg, u16* __restrict__ xbf,
    int* __restrict__ counts, int* __restrict__ entries,
    float* __restrict__ wts) {
  __shared__ int   se0[32], se1[32];
  __shared__ float sw0[32], sw1[32];
  int t = threadIdx.x;
  int tl = t >> 3;                 // token slot 0..31
  int l8 = t & 7;
  int tok = blockIdx.x * 32 + tl;

  const float* xrow = x + (size_t)tok * ND;
  u16* xbrow = xbf + (size_t)tok * ND;
  float acc[8] = {};
#pragma unroll 4
  for (int i = 0; i < 32; ++i) {
    int d0 = l8 * 4 + i * 32;
    float4 xv = *(const float4*)&xrow[d0];
    uint2 p;
    p.x = (unsigned)f2bf(xv.x) | ((unsigned)f2bf(xv.y) << 16);
    p.y = (unsigned)f2bf(xv.z) | ((unsigned)f2bf(xv.w) << 16);
    *(uint2*)&xbrow[d0] = p;
    const float* wr = Wg + (size_t)d0 * NE;
#pragma unroll
    for (int j = 0; j < 4; ++j) {
      float xs = (j == 0) ? xv.x : (j == 1) ? xv.y : (j == 2) ? xv.z : xv.w;
      float4 w0 = *(const float4*)&wr[j * NE];
      float4 w1 = *(const float4*)&wr[j * NE + 4];
      acc[0] += xs * w0.x; acc[1] += xs * w0.y;
      acc[2] += xs * w0.z; acc[3] += xs * w0.w;
      acc[4] += xs * w1.x; acc[5] += xs * w1.y;
      acc[6] += xs * w1.z; acc[7] += xs * w1.w;
    }
  }
#pragma unroll
  for (int off = 4; off; off >>= 1)
#pragma unroll
    for (int k = 0; k < 8; ++k) acc[k] += __shfl_down(acc[k], off, 8);

  if (l8 == 0) {
    float best = -1e30f, second = -1e30f;
    int e0 = 0, e1 = 0;
#pragma unroll
    for (int i = 0; i < NE; ++i) {
      float L = acc[i] + bg[i];
      if (L > best) { second = best; e1 = e0; best = L; e0 = i; }
      else if (L > second) { second = L; e1 = i; }
    }
    float p1 = __expf(second - best);
    float inv = 1.f / (1.f + p1);
    se0[tl] = e0; se1[tl] = e1;
    sw0[tl] = inv; sw1[tl] = p1 * inv;
  }
  __syncthreads();

  if (t < NE) {
    int e = t;
    int c = 0;
#pragma unroll
    for (int k = 0; k < 32; ++k) c += (se0[k] == e) + (se1[k] == e);
    int pos = atomicAdd(&counts[e * 32], c);   // padded: 128 B per expert
    int base = blockIdx.x * 32;
    for (int k = 0; k < 32; ++k) {
      if (se0[k] == e) { entries[e * NTOK + pos] = (base + k) * 2;     wts[e * NTOK + pos] = sw0[k]; ++pos; }
      if (se1[k] == e) { entries[e * NTOK + pos] = (base + k) * 2 + 1; wts[e * NTOK + pos] = sw1[k]; ++pos; }
    }
  }
}

// ---------------------------------------------------------------------------
// GEMM1: relu(X*W1 + b1) -> hbuf. BK=32, conflict-free swizzle,
// base-pointer + const-offset fragment reads. XCD-pinned: e = b&7.
// ---------------------------------------------------------------------------
__global__ __launch_bounds__(256) void gemm1_kernel(
    const u16* __restrict__ xbf, const u16* __restrict__ w1t,
    const float* __restrict__ b1, const int* __restrict__ counts,
    const int* __restrict__ entries, u16* __restrict__ hbuf) {
  int b = blockIdx.x;
  int e = b & 7;
  int r = b >> 3;
  int m0 = (r >> 4) * BM;          // NH/BN = 16 n-tiles innermost
  int n0 = (r & 15) * BN;
  int cnt = counts[e * 32];
  if (m0 >= cnt) return;
  int rem = cnt - m0; if (rem > BM) rem = BM;

  __shared__ u16 As[BM * BK];   // 8 KB
  __shared__ u16 Bs[BN * BK];   // 8 KB
  __shared__ int ent_s[BM];

  int t = threadIdx.x;
  if (t < BM) ent_s[t] = (t < rem) ? entries[e * NTOK + m0 + t] : entries[e * NTOK];
  __syncthreads();

  int lane = t & 63, wv = t >> 6;
  int rl0 = wv * 32 + (lane >> 2);         // staging rows
  int rl1 = rl0 + 16;
  int pg = (((lane & 3) ^ ((rl0 >> 1) & 3))) * 8;   // swizzled GLOBAL chunk
  const u16* gA0 = xbf + (size_t)(ent_s[rl0] >> 1) * ND + pg;
  const u16* gA1 = xbf + (size_t)(ent_s[rl1] >> 1) * ND + pg;
  const u16* Bbase = w1t + (size_t)e * NH * ND + (size_t)n0 * ND;
  const u16* gB0 = Bbase + (size_t)rl0 * ND + pg;
  const u16* gB1 = Bbase + (size_t)rl1 * ND + pg;
  u16* lA0 = As + (wv * 32) * BK;          // wave-uniform LDS bases
  u16* lA1 = As + (wv * 32 + 16) * BK;
  u16* lB0 = Bs + (wv * 32) * BK;
  u16* lB1 = Bs + (wv * 32 + 16) * BK;

  int waveM = (wv >> 1) * 64, waveN = (wv & 1) * 64;
  int rA = lane & 15, quad = lane >> 4;
  int cR = (quad ^ ((rA >> 1) & 3)) * 8;   // read-side phys chunk
  const u16* aBase = &As[(waveM + rA) * BK + cR];
  const u16* bBase = &Bs[(waveN + rA) * BK + cR];

  floatx4 acc[4][4] = {};
  for (int k0 = 0; k0 < ND; k0 += BK) {
    async16(gA0 + k0, lA0);
    async16(gA1 + k0, lA1);
    async16(gB0 + k0, lB0);
    async16(gB1 + k0, lB1);
    __syncthreads();
    short8 a[4], bb[4];
#pragma unroll
    for (int i = 0; i < 4; ++i) {
      a[i]  = *(const short8*)(aBase + i * (16 * BK));
      bb[i] = *(const short8*)(bBase + i * (16 * BK));
    }
#pragma unroll
    for (int i = 0; i < 4; ++i)
#pragma unroll
      for (int j = 0; j < 4; ++j)
        acc[i][j] = __builtin_amdgcn_mfma_f32_16x16x32_bf16(a[i], bb[j], acc[i][j], 0, 0, 0);
    __syncthreads();
  }

#pragma unroll
  for (int i = 0; i < 4; ++i)
#pragma unroll
    for (int rr = 0; rr < 4; ++rr) {
      int lm = waveM + i * 16 + quad * 4 + rr;
      if (lm >= rem) continue;
      int ent = ent_s[lm];
      u16* dst = hbuf + (size_t)ent * NH + n0;
#pragma unroll
      for (int j = 0; j < 4; ++j) {
        int col = waveN + j * 16 + rA;
        float v = acc[i][j][rr] + b1[e * NH + n0 + col];
        dst[col] = f2bf(fmaxf(v, 0.f));
      }
    }
}

// ---------------------------------------------------------------------------
// GEMM2: eo[entry] = (H*W2 + b2) * gate_w. Same structure, K=NH.
// ---------------------------------------------------------------------------
__global__ __launch_bounds__(256) void gemm2_kernel(
    const u16* __restrict__ hbuf, const u16* __restrict__ w2t,
    const float* __restrict__ b2, const int* __restrict__ counts,
    const int* __restrict__ entries, const float* __restrict__ wts,
    u16* __restrict__ eo) {
  int b = blockIdx.x;
  int e = b & 7;
  int r = b >> 3;
  int m0 = (r >> 3) * BM;          // NO/BN = 8 n-tiles innermost
  int n0 = (r & 7) * BN;
  int cnt = counts[e * 32];
  if (m0 >= cnt) return;
  int rem = cnt - m0; if (rem > BM) rem = BM;

  __shared__ u16 As[BM * BK];
  __shared__ u16 Bs[BN * BK];
  __shared__ int ent_s[BM];
  __shared__ float w_s[BM];

  int t = threadIdx.x;
  if (t < BM) {
    int src = (t < rem) ? (e * NTOK + m0 + t) : (e * NTOK);
    ent_s[t] = entries[src];
    w_s[t] = wts[src];
  }
  __syncthreads();

  int lane = t & 63, wv = t >> 6;
  int rl0 = wv * 32 + (lane >> 2);
  int rl1 = rl0 + 16;
  int pg = (((lane & 3) ^ ((rl0 >> 1) & 3))) * 8;
  const u16* gA0 = hbuf + (size_t)ent_s[rl0] * NH + pg;
  const u16* gA1 = hbuf + (size_t)ent_s[rl1] * NH + pg;
  const u16* Bbase = w2t + (size_t)e * NO * NH + (size_t)n0 * NH;
  const u16* gB0 = Bbase + (size_t)rl0 * NH + pg;
  const u16* gB1 = Bbase + (size_t)rl1 * NH + pg;
  u16* lA0 = As + (wv * 32) * BK;
  u16* lA1 = As + (wv * 32 + 16) * BK;
  u16* lB0 = Bs + (wv * 32) * BK;
  u16* lB1 = Bs + (wv * 32 + 16) * BK;

  int waveM = (wv >> 1) * 64, waveN = (wv & 1) * 64;
  int rA = lane & 15, quad = lane >> 4;
  int cR = (quad ^ ((rA >> 1) & 3)) * 8;
  const u16* aBase = &As[(waveM + rA) * BK + cR];
  const u16* bBase = &Bs[(waveN + rA) * BK + cR];

  floatx4 acc[4][4] = {};
  for (int k0 = 0; k0 < NH; k0 += BK) {
    async16(gA0 + k0, lA0);
    async16(gA1 + k0, lA1);
    async16(gB0 + k0, lB0);
    async16(gB1 + k0, lB1);
    __syncthreads();
    short8 a[4], bb[4];
#pragma unroll
    for (int i = 0; i < 4; ++i) {
      a[i]  = *(const short8*)(aBase + i * (16 * BK));
      bb[i] = *(const short8*)(bBase + i * (16 * BK));
    }
#pragma unroll
    for (int i = 0; i < 4; ++i)
#pragma unroll
      for (int j = 0; j < 4; ++j)
        acc[i][j] = __builtin_amdgcn_mfma_f32_16x16x32_bf16(a[i], bb[j], acc[i][j], 0, 0, 0);
    __syncthreads();
  }

#pragma unroll
  for (int i = 0; i < 4; ++i)
#pragma unroll
    for (int rr = 0; rr < 4; ++rr) {
      int lm = waveM + i * 16 + quad * 4 + rr;
      if (lm >= rem) continue;
      int ent = ent_s[lm];
      float w = w_s[lm];
      u16* dst = eo + (size_t)ent * NO + n0;
#pragma unroll
      for (int j = 0; j < 4; ++j) {
        int col = waveN + j * 16 + rA;
        float v = (acc[i][j][rr] + b2[e * NO + n0 + col]) * w;
        dst[col] = f2bf(v);
      }
    }
}

// ---------------------------------------------------------------------------
// Combine: out[tok] = eo[2*tok] + eo[2*tok+1]; 8 outputs/thread, uint4 loads.
// ---------------------------------------------------------------------------
__global__ __launch_bounds__(256) void combine_kernel(
    const u16* __restrict__ eo, float* __restrict__ out) {
  size_t idx = (size_t)blockIdx.x * 256 + threadIdx.x;  // one per 8 outputs
  size_t tok = idx >> 7;                                // NO/8 = 128 per token
  int oq = (int)(idx & 127) * 8;
  const u16* p0 = eo + (tok * 2) * NO + oq;
  const u16* p1 = p0 + NO;
  uint4 ua = *(const uint4*)p0;
  uint4 ub = *(const uint4*)p1;
  float* dst = out + tok * NO + oq;
  float4 o0, o1;
  o0.x = bf2f(ua.x & 0xffff) + bf2f(ub.x & 0xffff);
  o0.y = bf2f(ua.x >> 16)    + bf2f(ub.x >> 16);
  o0.z = bf2f(ua.y & 0xffff) + bf2f(ub.y & 0xffff);
  o0.w = bf2f(ua.y >> 16)    + bf2f(ub.y >> 16);
  o1.x = bf2f(ua.z & 0xffff) + bf2f(ub.z & 0xffff);
  o1.y = bf2f(ua.z >> 16)    + bf2f(ub.z >> 16);
  o1.z = bf2f(ua.w & 0xffff) + bf2f(ub.w & 0xffff);
  o1.w = bf2f(ua.w >> 16)    + bf2f(ub.w >> 16);
  *(float4*)dst = o0;
  *(float4*)(dst + 4) = o1;
}

// ---------------------------------------------------------------------------
extern "C" void kernel_launch(void* const* d_in, const int* in_sizes, int n_in,
                              void* d_out, int out_size, void* d_ws, size_t ws_size,
                              hipStream_t stream) {
  (void)in_sizes; (void)n_in; (void)out_size; (void)ws_size;
  const float* x  = (const float*)d_in[0];
  const float* Wg = (const float*)d_in[2];
  const float* bg = (const float*)d_in[3];
  const float* W1 = (const float*)d_in[4];
  const float* b1 = (const float*)d_in[5];
  const float* W2 = (const float*)d_in[6];
  const float* b2 = (const float*)d_in[7];
  float* out = (float*)d_out;

  char* ws = (char*)d_ws;
  size_t off = 0;
  int*   counts  = (int*)(ws + off);   off += NE * 32 * 4;               // padded
  int*   entries = (int*)(ws + off);   off += (size_t)NE * NTOK * 4;
  float* wts     = (float*)(ws + off); off += (size_t)NE * NTOK * 4;
  u16*   xbf     = (u16*)(ws + off);   off += (size_t)NTOK * ND * 2;
  u16*   w1t     = (u16*)(ws + off);   off += (size_t)NE * NH * ND * 2;
  u16*   w2t     = (u16*)(ws + off);   off += (size_t)NE * NO * NH * 2;
  u16*   hbuf    = (u16*)(ws + off);   off += (size_t)NTOK * 2 * NH * 2;
  u16*   eo      = w1t;  // alias: w1t dead after gemm1

  hipMemsetAsync(counts, 0, NE * 32 * 4, stream);

  transpose_cvt<<<dim3(NH / 64, ND / 64, NE), 256, 0, stream>>>(W1, w1t, ND, NH);
  transpose_cvt<<<dim3(NO / 64, NH / 64, NE), 256, 0, stream>>>(W2, w2t, NH, NO);
  router_kernel<<<NTOK / 32, 256, 0, stream>>>(x, Wg, bg, xbf, counts, entries, wts);
  gemm1_kernel<<<NE * (NTOK / BM) * (NH / BN), 256, 0, stream>>>(xbf, w1t, b1, counts, entries, hbuf);
  gemm2_kernel<<<NE * (NTOK / BM) * (NO / BN), 256, 0, stream>>>(hbuf, w2t, b2, counts, entries, wts, eo);
  combine_kernel<<<(NTOK * NO / 8) / 256, 256, 0, stream>>>(eo, out);
}